// Round 2
// baseline (590.746 us; speedup 1.0000x reference)
//
#include <hip/hip_runtime.h>
#include <hip/hip_cooperative_groups.h>

namespace cg = cooperative_groups;

constexpr int kB = 32;
constexpr int kC = 512;
constexpr int kS = 56 * 56;   // 3136
constexpr int kP = 64;
constexpr float kEps = 1e-3f;

constexpr int kST = 64;          // spatial tile per job (16 float4 per thread-slice)
constexpr int kNB = kS / kST;    // 49 tiles per batch
constexpr int kJobs = kB * kNB;  // 1568
static_assert(kS % kST == 0, "tile must divide S");

typedef float f4v __attribute__((ext_vector_type(4)));

// ---------------------------------------------------------------------------
// Single persistent cooperative kernel:
//   phase A: register-resident x-tiles -> mask -> local softmax -> partial ctx
//   grid sync
//   phase B: blocks 0..31 combine tile partials + tiny MLP -> add[b][c]
//   grid sync
//   phase C: out = x + gamma*add (x re-read hits L3: 205 MB < 256 MB L3)
// Grid = 392 blocks x 512 thr: 1568 jobs / 392 = exactly 4 jobs/block.
// ---------------------------------------------------------------------------
__global__ __launch_bounds__(512, 4)
void k_gca(const float* __restrict__ x, const float* __restrict__ wm,
           const float* __restrict__ w1, const float* __restrict__ b1,
           const float* __restrict__ ln_g, const float* __restrict__ ln_b,
           const float* __restrict__ w2, const float* __restrict__ b2,
           const float* __restrict__ gamma, float* __restrict__ out,
           float* __restrict__ pc, float* __restrict__ pmz,
           float* __restrict__ add) {
    __shared__ float swm[kC];
    __shared__ f4v   pmw4[8][16];      // per-wave mask partials (8 waves x 64 s)
    __shared__ f4v   es4[kST / 4];     // exp(mask - M_loc)
    // phase B scratch (disjoint liveness, coexists fine: ~9.4 KB total)
    __shared__ float scale[kNB];
    __shared__ float ctx[kC];
    __shared__ float hp[kP][9];
    __shared__ float hid[kP];

    const int t  = threadIdx.x;
    const int si = t & 15;             // which float4 of the 64-s tile
    const int c0 = t >> 4;             // 0..31
    const int w  = t >> 6;             // wave id 0..7
    const int l  = t & 63;             // lane id

    swm[t] = wm[t];                    // kC == 512 == blockDim
    __syncthreads();

    // ======================= phase A =======================
    for (int job = blockIdx.x; job < kJobs; job += gridDim.x) {
        const int b    = job / kNB;
        const int tile = job - b * kNB;
        const float* xb = x + (size_t)b * kC * kS + tile * kST + si * 4;

        // register tile: 16 float4 (64 VGPR), coalesced 256B quarter-wave rows
        f4v xt[16];
#pragma unroll
        for (int j = 0; j < 16; ++j)
            xt[j] = *(const f4v*)(xb + (size_t)(c0 + 32 * j) * kS);

        // mask partials over this thread's 16 c's
        float m0 = 0.f, m1 = 0.f, m2 = 0.f, m3 = 0.f;
#pragma unroll
        for (int j = 0; j < 16; ++j) {
            const float wv = swm[c0 + 32 * j];
            m0 += xt[j].x * wv; m1 += xt[j].y * wv;
            m2 += xt[j].z * wv; m3 += xt[j].w * wv;
        }
#pragma unroll
        for (int off = 16; off <= 32; off <<= 1) {
            m0 += __shfl_xor(m0, off); m1 += __shfl_xor(m1, off);
            m2 += __shfl_xor(m2, off); m3 += __shfl_xor(m3, off);
        }
        if (l < 16) pmw4[w][si] = (f4v){m0, m1, m2, m3};
        __syncthreads();

        // wave 0: combine 8 wave-partials, local softmax over 64 s
        if (t < kST) {
            const float* pmf = (const float*)pmw4;
            float v = 0.f;
#pragma unroll
            for (int ww = 0; ww < 8; ++ww) v += pmf[ww * kST + t];
            float mx = v;
#pragma unroll
            for (int off = 1; off < 64; off <<= 1) mx = fmaxf(mx, __shfl_xor(mx, off));
            const float e = expf(v - mx);
            float z = e;
#pragma unroll
            for (int off = 1; off < 64; off <<= 1) z += __shfl_xor(z, off);
            ((float*)es4)[t] = e;
            if (t == 0) {
                pmz[job * 2 + 0] = mx;
                pmz[job * 2 + 1] = z;
            }
        }
        __syncthreads();

        // context from the SAME registers
        const f4v e4 = es4[si];
        float* pco = pc + (size_t)job * kC;
#pragma unroll
        for (int j = 0; j < 16; ++j) {
            float a = xt[j].x * e4.x + xt[j].y * e4.y + xt[j].z * e4.z + xt[j].w * e4.w;
            a += __shfl_xor(a, 1); a += __shfl_xor(a, 2);
            a += __shfl_xor(a, 4); a += __shfl_xor(a, 8);
            if (si == 0) pco[c0 + 32 * j] = a;
        }
        // REQUIRED in persistent form: a fast wave must not overwrite pmw4
        // for job k+1 while wave 0 still reads it for job k.
        __syncthreads();
    }

    __threadfence();
    cg::this_grid().sync();

    // ======================= phase B (blocks 0..31) =======================
    if (blockIdx.x < kB) {
        const int b = blockIdx.x;

        if (t < 64) {
            const float m1 = (t < kNB) ? pmz[(b * kNB + t) * 2] : -INFINITY;
            float m = m1;
            for (int off = 32; off; off >>= 1) m = fmaxf(m, __shfl_xor(m, off));
            const float e1 = (t < kNB) ? expf(m1 - m) : 0.f;
            float z = 0.f;
            if (t < kNB) z = pmz[(b * kNB + t) * 2 + 1] * e1;
            for (int off = 32; off; off >>= 1) z += __shfl_xor(z, off);
            const float inv = 1.f / z;
            if (t < kNB) scale[t] = e1 * inv;
        }
        __syncthreads();

        // ctx[c] = sum_i pc[i][c] * scale[i]
        {
            float acc = 0.f;
            for (int i = 0; i < kNB; ++i)
                acc += pc[((size_t)b * kNB + i) * kC + t] * scale[i];
            ctx[t] = acc;
        }
        __syncthreads();

        // hid partials: p = t&63, chunk k = t>>6 sums 64 c's
        {
            const int p = t & 63, k = t >> 6;
            const float* w1p = w1 + p * kC + k * 64;
            const float* cxp = ctx + k * 64;
            float acc = 0.f;
#pragma unroll 8
            for (int i = 0; i < 64; ++i) acc += w1p[i] * cxp[i];
            hp[p][k] = acc;
        }
        __syncthreads();

        if (t < 64) {
            float h = b1[t];
#pragma unroll
            for (int k = 0; k < 8; ++k) h += hp[t][k];
            float mu = h;
            for (int off = 32; off; off >>= 1) mu += __shfl_xor(mu, off);
            mu *= (1.f / kP);
            const float d = h - mu;
            float var = d * d;
            for (int off = 32; off; off >>= 1) var += __shfl_xor(var, off);
            var *= (1.f / kP);
            const float hv = d * rsqrtf(var + kEps) * ln_g[t] + ln_b[t];
            hid[t] = fmaxf(hv, 0.f);
        }
        __syncthreads();

        {
            float a = b2[t];
            const float* w2c = w2 + t * kP;
#pragma unroll
            for (int p = 0; p < kP; ++p) a += w2c[p] * hid[p];
            add[b * kC + t] = a;
        }
    }

    __threadfence();
    cg::this_grid().sync();

    // ======================= phase C =======================
    const float g = gamma[0];
    const unsigned n4 = (unsigned)((size_t)kB * kC * kS / 4);   // 12.85M < 2^32
    const unsigned stride = gridDim.x * 512u;
    for (unsigned i4 = blockIdx.x * 512u + t; i4 < n4; i4 += stride) {
        const unsigned bc = i4 / (kS / 4);    // 32-bit magic-mul div
        const float a = g * add[bc];
        f4v xv = ((const f4v*)x)[i4];
        f4v o = {xv.x + a, xv.y + a, xv.z + a, xv.w + a};
        __builtin_nontemporal_store(o, (f4v*)out + i4);
    }
}

// ---------------------------------------------------------------------------
// Fallback path (non-cooperative), kept verbatim in case cooperative launch
// is rejected under graph capture.
// ---------------------------------------------------------------------------
__global__ __launch_bounds__(512, 4)
void k_fused_pass(const float* __restrict__ x, const float* __restrict__ wm,
                  float* __restrict__ pc, float* __restrict__ pmz) {
    __shared__ float swm[kC];
    __shared__ f4v   pmw4[8][16];
    __shared__ f4v   es4[kST / 4];

    const int b    = blockIdx.y;
    const int tile = blockIdx.x;
    const int t    = threadIdx.x;
    const int si   = t & 15;
    const int c0   = t >> 4;
    const int w    = t >> 6;
    const int l    = t & 63;

    swm[t] = wm[t];
    __syncthreads();

    const float* xb = x + (size_t)b * kC * kS + tile * kST + si * 4;
    f4v xt[16];
#pragma unroll
    for (int j = 0; j < 16; ++j)
        xt[j] = *(const f4v*)(xb + (size_t)(c0 + 32 * j) * kS);

    float m0 = 0.f, m1 = 0.f, m2 = 0.f, m3 = 0.f;
#pragma unroll
    for (int j = 0; j < 16; ++j) {
        const float wv = swm[c0 + 32 * j];
        m0 += xt[j].x * wv; m1 += xt[j].y * wv;
        m2 += xt[j].z * wv; m3 += xt[j].w * wv;
    }
#pragma unroll
    for (int off = 16; off <= 32; off <<= 1) {
        m0 += __shfl_xor(m0, off); m1 += __shfl_xor(m1, off);
        m2 += __shfl_xor(m2, off); m3 += __shfl_xor(m3, off);
    }
    if (l < 16) pmw4[w][si] = (f4v){m0, m1, m2, m3};
    __syncthreads();

    if (t < kST) {
        const float* pmf = (const float*)pmw4;
        float v = 0.f;
#pragma unroll
        for (int ww = 0; ww < 8; ++ww) v += pmf[ww * kST + t];
        float mx = v;
#pragma unroll
        for (int off = 1; off < 64; off <<= 1) mx = fmaxf(mx, __shfl_xor(mx, off));
        const float e = expf(v - mx);
        float z = e;
#pragma unroll
        for (int off = 1; off < 64; off <<= 1) z += __shfl_xor(z, off);
        ((float*)es4)[t] = e;
        if (t == 0) {
            pmz[(b * kNB + tile) * 2 + 0] = mx;
            pmz[(b * kNB + tile) * 2 + 1] = z;
        }
    }
    __syncthreads();

    const f4v e4 = es4[si];
    float* pco = pc + ((size_t)b * kNB + tile) * kC;
#pragma unroll
    for (int j = 0; j < 16; ++j) {
        float a = xt[j].x * e4.x + xt[j].y * e4.y + xt[j].z * e4.z + xt[j].w * e4.w;
        a += __shfl_xor(a, 1); a += __shfl_xor(a, 2);
        a += __shfl_xor(a, 4); a += __shfl_xor(a, 8);
        if (si == 0) pco[c0 + 32 * j] = a;
    }
}

__global__ __launch_bounds__(512)
void k_combine_mlp(const float* __restrict__ pc, const float* __restrict__ pmz,
                   const float* __restrict__ w1, const float* __restrict__ b1,
                   const float* __restrict__ ln_g, const float* __restrict__ ln_b,
                   const float* __restrict__ w2, const float* __restrict__ b2,
                   float* __restrict__ add) {
    const int b = blockIdx.x;
    const int t = threadIdx.x;
    __shared__ float scale[kNB];
    __shared__ float ctx[kC];
    __shared__ float hp[kP][9];
    __shared__ float hid[kP];

    if (t < 64) {
        const float m1 = (t < kNB) ? pmz[(b * kNB + t) * 2] : -INFINITY;
        float m = m1;
        for (int off = 32; off; off >>= 1) m = fmaxf(m, __shfl_xor(m, off));
        const float e1 = (t < kNB) ? expf(m1 - m) : 0.f;
        float z = 0.f;
        if (t < kNB) z = pmz[(b * kNB + t) * 2 + 1] * e1;
        for (int off = 32; off; off >>= 1) z += __shfl_xor(z, off);
        const float inv = 1.f / z;
        if (t < kNB) scale[t] = e1 * inv;
    }
    __syncthreads();

    {
        float acc = 0.f;
        for (int i = 0; i < kNB; ++i)
            acc += pc[((size_t)b * kNB + i) * kC + t] * scale[i];
        ctx[t] = acc;
    }
    __syncthreads();

    {
        const int p = t & 63, k = t >> 6;
        const float* w1p = w1 + p * kC + k * 64;
        const float* cxp = ctx + k * 64;
        float acc = 0.f;
#pragma unroll 8
        for (int i = 0; i < 64; ++i) acc += w1p[i] * cxp[i];
        hp[p][k] = acc;
    }
    __syncthreads();

    if (t < 64) {
        float h = b1[t];
#pragma unroll
        for (int k = 0; k < 8; ++k) h += hp[t][k];
        float mu = h;
        for (int off = 32; off; off >>= 1) mu += __shfl_xor(mu, off);
        mu *= (1.f / kP);
        const float d = h - mu;
        float var = d * d;
        for (int off = 32; off; off >>= 1) var += __shfl_xor(var, off);
        var *= (1.f / kP);
        const float hv = d * rsqrtf(var + kEps) * ln_g[t] + ln_b[t];
        hid[t] = fmaxf(hv, 0.f);
    }
    __syncthreads();

    {
        float a = b2[t];
        const float* w2c = w2 + t * kP;
#pragma unroll
        for (int p = 0; p < kP; ++p) a += w2c[p] * hid[p];
        add[b * kC + t] = a;
    }
}

__global__ __launch_bounds__(256)
void k_out(const float* __restrict__ x, const float* __restrict__ add,
           const float* __restrict__ gamma, float* __restrict__ out) {
    const size_t i4 = (size_t)blockIdx.x * blockDim.x + threadIdx.x;
    const size_t n4 = (size_t)kB * kC * kS / 4;
    if (i4 >= n4) return;
    const int bc = (int)(i4 / (kS / 4));
    const float a = gamma[0] * add[bc];
    f4v xv = ((const f4v*)x)[i4];
    f4v o = {xv.x + a, xv.y + a, xv.z + a, xv.w + a};
    __builtin_nontemporal_store(o, (f4v*)out + i4);
}

extern "C" void kernel_launch(void* const* d_in, const int* in_sizes, int n_in,
                              void* d_out, int out_size, void* d_ws, size_t ws_size,
                              hipStream_t stream) {
    const float* x     = (const float*)d_in[0];
    const float* wm    = (const float*)d_in[1];
    // d_in[2] = bm: uniform pre-softmax shift -> no-op, skipped
    const float* w1    = (const float*)d_in[3];
    const float* b1    = (const float*)d_in[4];
    const float* ln_g  = (const float*)d_in[5];
    const float* ln_b  = (const float*)d_in[6];
    const float* w2    = (const float*)d_in[7];
    const float* b2    = (const float*)d_in[8];
    const float* gamma = (const float*)d_in[9];
    float* out = (float*)d_out;

    float* ws  = (float*)d_ws;
    float* pc  = ws;                               // kJobs*kC floats (3.2 MB)
    float* pmz = pc + (size_t)kJobs * kC;          // kJobs*2 floats
    float* add = pmz + (size_t)kJobs * 2;          // kB*kC floats

    // Size the cooperative grid for guaranteed co-residency. 392 blocks
    // gives exactly 4 phase-A jobs per block (1568/392).
    static int grid = 0;
    if (grid == 0) {
        int perCU = 0;
        if (hipOccupancyMaxActiveBlocksPerMultiprocessor(&perCU, k_gca, 512, 0)
                != hipSuccess || perCU < 1)
            perCU = 1;
        const int maxB = perCU * 256;
        grid = (maxB >= 392) ? 392 : maxB;
    }

    void* args[] = {(void*)&x, (void*)&wm, (void*)&w1, (void*)&b1,
                    (void*)&ln_g, (void*)&ln_b, (void*)&w2, (void*)&b2,
                    (void*)&gamma, (void*)&out, (void*)&pc, (void*)&pmz,
                    (void*)&add};
    const hipError_t lerr = hipLaunchCooperativeKernel(
        reinterpret_cast<void*>(k_gca), dim3(grid), dim3(512), args, 0, stream);

    if (lerr != hipSuccess) {
        // fallback: original 3-kernel path
        k_fused_pass<<<dim3(kNB, kB), 512, 0, stream>>>(x, wm, pc, pmz);
        k_combine_mlp<<<kB, 512, 0, stream>>>(pc, pmz, w1, b1, ln_g, ln_b,
                                              w2, b2, add);
        const size_t n4 = (size_t)kB * kC * kS / 4;
        k_out<<<(unsigned)((n4 + 255) / 256), 256, 0, stream>>>(x, add, gamma, out);
    }
}

// Round 4
// 437.225 us; speedup vs baseline: 1.3511x; 1.3511x over previous
//
#include <hip/hip_runtime.h>

constexpr int kB = 32;
constexpr int kC = 512;
constexpr int kS = 56 * 56;   // 3136
constexpr int kP = 64;
constexpr float kEps = 1e-3f;

constexpr int kSG = 32;          // spatial elems per wave-group (= 128B row span)
constexpr int kNG = kS / kSG;    // 98 groups per batch
constexpr int kGPB = 2;          // waves (groups) per block -> 128-thread blocks
static_assert(kS % kSG == 0, "group must divide S");
static_assert(kNG % kGPB == 0, "block must divide groups");

typedef float f4v __attribute__((ext_vector_type(4)));

// ---------------------------------------------------------------------------
// Pass A v3: wave-independent, barrier-free streaming.
// One wave owns 32 consecutive s  x  all 512 c.  Lane (cg = l>>3, si = l&7):
//   loads  x[c = cg+8k][s0 + si*4 .. +3]  for k = 0..63
//   -> per load-instr: 8 full 128B lines (minimum request count, coalesced)
// mask[s]: FMA vs wm, shfl_xor over cg (8,16,32); softmax max/Z: shfl_xor over
// si (1,2,4). Context phase re-reads the same 64KB from L2 (hot: only ~300KB
// streams through the XCD L2 in between). No __syncthreads after wm stage,
// no wave0-serial section, no inter-wave coupling.
// ---------------------------------------------------------------------------
__global__ __launch_bounds__(128)
void k_pass_a(const float* __restrict__ x, const float* __restrict__ wm,
              float* __restrict__ pc, float* __restrict__ pmz) {
    __shared__ float swm[kC];
    const int t = threadIdx.x;
    swm[t]       = wm[t];
    swm[t + 128] = wm[t + 128];
    swm[t + 256] = wm[t + 256];
    swm[t + 384] = wm[t + 384];
    __syncthreads();

    const int b  = blockIdx.y;
    const int g  = blockIdx.x * kGPB + (t >> 6);   // this wave's s-group
    const int l  = t & 63;
    const int si = l & 7;                          // 4-s chunk within the 32-s group
    const int cg = l >> 3;                         // 0..7
    const int s0 = g * kSG;

    const float* xb = x + (size_t)b * kC * kS + (size_t)cg * kS + s0 + si * 4;

    // ---- phase 1: mask partials (lane covers c = cg + 8k, its 4 s-values) ----
    float m0 = 0.f, m1 = 0.f, m2 = 0.f, m3 = 0.f;
#pragma unroll 8
    for (int k = 0; k < 64; ++k) {
        const f4v v = *(const f4v*)(xb + (size_t)8 * k * kS);
        const float wv = swm[cg + 8 * k];
        m0 += v.x * wv; m1 += v.y * wv; m2 += v.z * wv; m3 += v.w * wv;
    }
    // sum over the 8 cg groups (lanes differing in bits 3..5)
#pragma unroll
    for (int off = 8; off <= 32; off <<= 1) {
        m0 += __shfl_xor(m0, off); m1 += __shfl_xor(m1, off);
        m2 += __shfl_xor(m2, off); m3 += __shfl_xor(m3, off);
    }
    // wave-local softmax over the 32 s: max over si chunks (bits 0..2)
    float mm = fmaxf(fmaxf(m0, m1), fmaxf(m2, m3));
    mm = fmaxf(mm, __shfl_xor(mm, 1));
    mm = fmaxf(mm, __shfl_xor(mm, 2));
    mm = fmaxf(mm, __shfl_xor(mm, 4));
    const float e0 = expf(m0 - mm), e1 = expf(m1 - mm);
    const float e2 = expf(m2 - mm), e3 = expf(m3 - mm);
    float z = e0 + e1 + e2 + e3;
    z += __shfl_xor(z, 1); z += __shfl_xor(z, 2); z += __shfl_xor(z, 4);
    if (l == 0) {
        pmz[(b * kNG + g) * 2 + 0] = mm;
        pmz[(b * kNG + g) * 2 + 1] = z;
    }

    // ---- phase 2: context partials, re-read from L2 ----
    float* pco = pc + ((size_t)b * kNG + g) * kC;
#pragma unroll 8
    for (int k = 0; k < 64; ++k) {
        const f4v v = *(const f4v*)(xb + (size_t)8 * k * kS);
        float p = v.x * e0 + v.y * e1 + v.z * e2 + v.w * e3;
        p += __shfl_xor(p, 1); p += __shfl_xor(p, 2); p += __shfl_xor(p, 4);
        if (si == 0) pco[cg + 8 * k] = p;   // 8 lanes -> 8 consecutive floats
    }
}

// ---------------------------------------------------------------------------
// Pass B: per batch — combine 98 group-partials with global softmax rescale,
// then the tiny MLP (w1 -> LN -> ReLU -> w2), gamma folded into the output.
// ---------------------------------------------------------------------------
__global__ __launch_bounds__(512)
void k_combine_mlp(const float* __restrict__ pc, const float* __restrict__ pmz,
                   const float* __restrict__ w1, const float* __restrict__ b1,
                   const float* __restrict__ ln_g, const float* __restrict__ ln_b,
                   const float* __restrict__ w2, const float* __restrict__ b2,
                   const float* __restrict__ gamma, float* __restrict__ add) {
    const int b = blockIdx.x;
    const int t = threadIdx.x;
    __shared__ float scale[kNG];     // exp(M_i - M)/Z
    __shared__ float ctx[kC];
    __shared__ float hp[kP][9];      // hid partials (pad 9: bank-spread)
    __shared__ float hid[kP];

    // wave 0: global max + Z over 98 groups (two elems per lane)
    if (t < 64) {
        const float m1 = (t      < kNG) ? pmz[(b * kNG + t     ) * 2] : -INFINITY;
        const float m2 = (t + 64 < kNG) ? pmz[(b * kNG + t + 64) * 2] : -INFINITY;
        float m = fmaxf(m1, m2);
        for (int off = 32; off; off >>= 1) m = fmaxf(m, __shfl_xor(m, off));
        const float e1 = (t      < kNG) ? expf(m1 - m) : 0.f;
        const float e2 = (t + 64 < kNG) ? expf(m2 - m) : 0.f;
        float z = 0.f;
        if (t      < kNG) z += pmz[(b * kNG + t     ) * 2 + 1] * e1;
        if (t + 64 < kNG) z += pmz[(b * kNG + t + 64) * 2 + 1] * e2;
        for (int off = 32; off; off >>= 1) z += __shfl_xor(z, off);
        const float inv = 1.f / z;
        if (t      < kNG) scale[t]      = e1 * inv;
        if (t + 64 < kNG) scale[t + 64] = e2 * inv;
    }
    __syncthreads();

    // ctx[c] = sum_i pc[i][c] * scale[i]   (coalesced over c)
    {
        float acc = 0.f;
        for (int i = 0; i < kNG; ++i)
            acc += pc[((size_t)b * kNG + i) * kC + t] * scale[i];
        ctx[t] = acc;
    }
    __syncthreads();

    // hid partials: p = t&63, chunk k = t>>6 sums 64 c's (ctx read = broadcast)
    {
        const int p = t & 63, k = t >> 6;
        const float* w1p = w1 + p * kC + k * 64;
        const float* cxp = ctx + k * 64;
        float acc = 0.f;
#pragma unroll 8
        for (int i = 0; i < 64; ++i) acc += w1p[i] * cxp[i];
        hp[p][k] = acc;
    }
    __syncthreads();

    if (t < 64) {
        float h = b1[t];
#pragma unroll
        for (int k = 0; k < 8; ++k) h += hp[t][k];
        float mu = h;
        for (int off = 32; off; off >>= 1) mu += __shfl_xor(mu, off);
        mu *= (1.f / kP);
        const float d = h - mu;
        float var = d * d;
        for (int off = 32; off; off >>= 1) var += __shfl_xor(var, off);
        var *= (1.f / kP);
        const float hv = d * rsqrtf(var + kEps) * ln_g[t] + ln_b[t];
        hid[t] = fmaxf(hv, 0.f);
    }
    __syncthreads();

    // add[c] = gamma * (b2[c] + w2[c,:]·hid)   — gamma folded here
    {
        float a = b2[t];
        const float* w2c = w2 + t * kP;
#pragma unroll
        for (int p = 0; p < kP; ++p) a += w2c[p] * hid[p];
        add[b * kC + t] = gamma[0] * a;
    }
}

// ---------------------------------------------------------------------------
// Pass C v2: out = x + add[bc] (gamma pre-folded). 3136 blocks x 256 thr,
// each thread exactly 16 f4, fully unrolled -> 16 independent loads in
// flight per thread (vs 1 before). Block covers 64KB contiguous.
// ---------------------------------------------------------------------------
constexpr int kOutBlocks = (kB * kC * kS / 4) / (256 * 16);   // 3136
static_assert(kOutBlocks * 256 * 16 == kB * kC * kS / 4, "exact tiling");

__global__ __launch_bounds__(256)
void k_out(const float* __restrict__ x, const float* __restrict__ addv,
           float* __restrict__ out) {
    const size_t base = (size_t)blockIdx.x * 4096 + threadIdx.x;
#pragma unroll
    for (int j = 0; j < 16; ++j) {
        const size_t i4 = base + (size_t)j * 256;
        const float a = addv[i4 / (kS / 4)];       // /784 -> magic-mul
        const f4v xv = ((const f4v*)x)[i4];
        const f4v o = {xv.x + a, xv.y + a, xv.z + a, xv.w + a};
        ((f4v*)out)[i4] = o;
    }
}

extern "C" void kernel_launch(void* const* d_in, const int* in_sizes, int n_in,
                              void* d_out, int out_size, void* d_ws, size_t ws_size,
                              hipStream_t stream) {
    const float* x     = (const float*)d_in[0];
    const float* wm    = (const float*)d_in[1];
    // d_in[2] = bm: uniform pre-softmax shift -> no-op, skipped
    const float* w1    = (const float*)d_in[3];
    const float* b1    = (const float*)d_in[4];
    const float* ln_g  = (const float*)d_in[5];
    const float* ln_b  = (const float*)d_in[6];
    const float* w2    = (const float*)d_in[7];
    const float* b2    = (const float*)d_in[8];
    const float* gamma = (const float*)d_in[9];
    float* out = (float*)d_out;

    float* ws  = (float*)d_ws;
    float* pc  = ws;                               // kB*kNG*kC floats (6.4 MB)
    float* pmz = pc + (size_t)kB * kNG * kC;       // kB*kNG*2 floats
    float* add = pmz + (size_t)kB * kNG * 2;       // kB*kC floats

    k_pass_a<<<dim3(kNG / kGPB, kB), kGPB * 64, 0, stream>>>(x, wm, pc, pmz);
    k_combine_mlp<<<kB, 512, 0, stream>>>(pc, pmz, w1, b1, ln_g, ln_b,
                                          w2, b2, gamma, add);
    k_out<<<kOutBlocks, 256, 0, stream>>>(x, add, out);
}

// Round 5
// 413.877 us; speedup vs baseline: 1.4273x; 1.0564x over previous
//
#include <hip/hip_runtime.h>

constexpr int kB = 32;
constexpr int kC = 512;
constexpr int kS = 56 * 56;   // 3136
constexpr int kP = 64;
constexpr float kEps = 1e-3f;

constexpr int kSG = 32;          // spatial elems per group (one block)
constexpr int kNG = kS / kSG;    // 98 groups per batch
constexpr int kCW = kC / 2;      // 256 channels per wave (2 waves/block)
static_assert(kS % kSG == 0, "group must divide S");

typedef float f4v __attribute__((ext_vector_type(4)));

// ---------------------------------------------------------------------------
// Pass A v4: register-resident tile, x read from HBM EXACTLY once.
// Block = 128 thr = 2 waves; one 32-s group per block. Wave w owns
// c in [w*256, w*256+256). Lane (cg = l>>3, si = l&7) holds
// x[c = w*256+cg+8k][s0+si*4 .. +3] for k = 0..31  -> 32 x float4 = 128 VGPR.
// Each load instruction covers 8 full 128B lines (8 rows x 128B).
//   phase 1: mask partial FMA vs wm; butterfly over cg (8,16,32);
//            one LDS exchange between the 2 waves -> full mask[32 s]
//   softmax: butterfly over si (1,2,4) -> es per lane's 4 s
//   phase 2: context FMA from the SAME registers; butterfly over si; store.
// The asm pin between the phases blocks load rematerialization (round-2
// evidence: without it, hipcc re-loads from global and VGPR_Count drops).
// ---------------------------------------------------------------------------
__global__ __launch_bounds__(128, 2)
void k_pass_a(const float* __restrict__ x, const float* __restrict__ wm,
              float* __restrict__ pc, float* __restrict__ pmz) {
    __shared__ float swm[kC];
    __shared__ f4v   pmw[2][8];        // inter-wave mask-partial exchange

    const int t  = threadIdx.x;
    const int w  = t >> 6;             // wave 0/1
    const int l  = t & 63;
    const int si = l & 7;              // 4-s chunk within the 32-s group
    const int cg = l >> 3;             // 0..7
    const int b  = blockIdx.y;
    const int g  = blockIdx.x;
    const int s0 = g * kSG;

    swm[t]       = wm[t];
    swm[t + 128] = wm[t + 128];
    swm[t + 256] = wm[t + 256];
    swm[t + 384] = wm[t + 384];

    const float* xb = x + (size_t)b * kC * kS
                        + (size_t)(w * kCW + cg) * kS + s0 + si * 4;

    // ---- single global read: 32 independent loads issued back-to-back ----
    f4v xt[32];
#pragma unroll
    for (int k = 0; k < 32; ++k)
        xt[k] = *(const f4v*)(xb + (size_t)(8 * k) * kS);

    __syncthreads();                   // swm ready (also drains the loads)

    // ---- phase 1: mask partials over this wave's 256 c ----
    float m0 = 0.f, m1 = 0.f, m2 = 0.f, m3 = 0.f;
#pragma unroll
    for (int k = 0; k < 32; ++k) {
        const float wv = swm[w * kCW + cg + 8 * k];
        m0 += xt[k].x * wv; m1 += xt[k].y * wv;
        m2 += xt[k].z * wv; m3 += xt[k].w * wv;
    }

    // pin the tile: forbid rematerialization of the global loads past here
#pragma unroll
    for (int k = 0; k < 32; ++k) asm volatile("" : "+v"(xt[k]));

    // sum over the 8 cg groups (lane bits 3..5)
#pragma unroll
    for (int off = 8; off <= 32; off <<= 1) {
        m0 += __shfl_xor(m0, off); m1 += __shfl_xor(m1, off);
        m2 += __shfl_xor(m2, off); m3 += __shfl_xor(m3, off);
    }

    // exchange between the two waves: full 512-c mask
    if (l < 8) pmw[w][si] = (f4v){m0, m1, m2, m3};
    __syncthreads();
    {
        const f4v o = pmw[w ^ 1][si];
        m0 += o.x; m1 += o.y; m2 += o.z; m3 += o.w;
    }

    // ---- local softmax over the 32 s (lane bits 0..2 + in-lane 4) ----
    float mm = fmaxf(fmaxf(m0, m1), fmaxf(m2, m3));
    mm = fmaxf(mm, __shfl_xor(mm, 1));
    mm = fmaxf(mm, __shfl_xor(mm, 2));
    mm = fmaxf(mm, __shfl_xor(mm, 4));
    const float e0 = expf(m0 - mm), e1 = expf(m1 - mm);
    const float e2 = expf(m2 - mm), e3 = expf(m3 - mm);
    float z = e0 + e1 + e2 + e3;
    z += __shfl_xor(z, 1); z += __shfl_xor(z, 2); z += __shfl_xor(z, 4);
    if (t == 0) {
        pmz[(b * kNG + g) * 2 + 0] = mm;
        pmz[(b * kNG + g) * 2 + 1] = z;
    }

    // ---- phase 2: context from the SAME registers ----
    float* pco = pc + ((size_t)b * kNG + g) * kC + w * kCW;
#pragma unroll
    for (int k = 0; k < 32; ++k) {
        float p = xt[k].x * e0 + xt[k].y * e1 + xt[k].z * e2 + xt[k].w * e3;
        p += __shfl_xor(p, 1); p += __shfl_xor(p, 2); p += __shfl_xor(p, 4);
        if (si == 0) pco[8 * k + cg] = p;   // 8 lanes -> 8 consecutive floats
    }
}

// ---------------------------------------------------------------------------
// Pass B: per batch — combine 98 group-partials with global softmax rescale,
// then the tiny MLP (w1 -> LN -> ReLU -> w2), gamma folded into the output.
// ---------------------------------------------------------------------------
__global__ __launch_bounds__(512)
void k_combine_mlp(const float* __restrict__ pc, const float* __restrict__ pmz,
                   const float* __restrict__ w1, const float* __restrict__ b1,
                   const float* __restrict__ ln_g, const float* __restrict__ ln_b,
                   const float* __restrict__ w2, const float* __restrict__ b2,
                   const float* __restrict__ gamma, float* __restrict__ add) {
    const int b = blockIdx.x;
    const int t = threadIdx.x;
    __shared__ float scale[kNG];     // exp(M_i - M)/Z
    __shared__ float ctx[kC];
    __shared__ float hp[kP][9];      // hid partials (pad 9: bank-spread)
    __shared__ float hid[kP];

    // wave 0: global max + Z over 98 groups (two elems per lane)
    if (t < 64) {
        const float m1 = (t      < kNG) ? pmz[(b * kNG + t     ) * 2] : -INFINITY;
        const float m2 = (t + 64 < kNG) ? pmz[(b * kNG + t + 64) * 2] : -INFINITY;
        float m = fmaxf(m1, m2);
        for (int off = 32; off; off >>= 1) m = fmaxf(m, __shfl_xor(m, off));
        const float e1 = (t      < kNG) ? expf(m1 - m) : 0.f;
        const float e2 = (t + 64 < kNG) ? expf(m2 - m) : 0.f;
        float z = 0.f;
        if (t      < kNG) z += pmz[(b * kNG + t     ) * 2 + 1] * e1;
        if (t + 64 < kNG) z += pmz[(b * kNG + t + 64) * 2 + 1] * e2;
        for (int off = 32; off; off >>= 1) z += __shfl_xor(z, off);
        const float inv = 1.f / z;
        if (t      < kNG) scale[t]      = e1 * inv;
        if (t + 64 < kNG) scale[t + 64] = e2 * inv;
    }
    __syncthreads();

    // ctx[c] = sum_i pc[i][c] * scale[i]   (coalesced over c)
    {
        float acc = 0.f;
        for (int i = 0; i < kNG; ++i)
            acc += pc[((size_t)b * kNG + i) * kC + t] * scale[i];
        ctx[t] = acc;
    }
    __syncthreads();

    // hid partials: p = t&63, chunk k = t>>6 sums 64 c's (ctx read = broadcast)
    {
        const int p = t & 63, k = t >> 6;
        const float* w1p = w1 + p * kC + k * 64;
        const float* cxp = ctx + k * 64;
        float acc = 0.f;
#pragma unroll 8
        for (int i = 0; i < 64; ++i) acc += w1p[i] * cxp[i];
        hp[p][k] = acc;
    }
    __syncthreads();

    if (t < 64) {
        float h = b1[t];
#pragma unroll
        for (int k = 0; k < 8; ++k) h += hp[t][k];
        float mu = h;
        for (int off = 32; off; off >>= 1) mu += __shfl_xor(mu, off);
        mu *= (1.f / kP);
        const float d = h - mu;
        float var = d * d;
        for (int off = 32; off; off >>= 1) var += __shfl_xor(var, off);
        var *= (1.f / kP);
        const float hv = d * rsqrtf(var + kEps) * ln_g[t] + ln_b[t];
        hid[t] = fmaxf(hv, 0.f);
    }
    __syncthreads();

    // add[c] = gamma * (b2[c] + w2[c,:]·hid)   — gamma folded here
    {
        float a = b2[t];
        const float* w2c = w2 + t * kP;
#pragma unroll
        for (int p = 0; p < kP; ++p) a += w2c[p] * hid[p];
        add[b * kC + t] = gamma[0] * a;
    }
}

// ---------------------------------------------------------------------------
// Pass C: out = x + add[bc] (gamma pre-folded). 3136 blocks x 256 thr,
// each thread exactly 16 f4, fully unrolled -> 16 independent load/store
// pairs in flight. x re-read is L3-resident (measured round 2: FETCH=204MB).
// ---------------------------------------------------------------------------
constexpr int kOutBlocks = (kB * kC * kS / 4) / (256 * 16);   // 3136
static_assert(kOutBlocks * 256 * 16 == kB * kC * kS / 4, "exact tiling");

__global__ __launch_bounds__(256)
void k_out(const float* __restrict__ x, const float* __restrict__ addv,
           float* __restrict__ out) {
    const size_t base = (size_t)blockIdx.x * 4096 + threadIdx.x;
#pragma unroll
    for (int j = 0; j < 16; ++j) {
        const size_t i4 = base + (size_t)j * 256;
        const float a = addv[i4 / (kS / 4)];       // /784 -> magic-mul
        const f4v xv = ((const f4v*)x)[i4];
        const f4v o = {xv.x + a, xv.y + a, xv.z + a, xv.w + a};
        ((f4v*)out)[i4] = o;
    }
}

extern "C" void kernel_launch(void* const* d_in, const int* in_sizes, int n_in,
                              void* d_out, int out_size, void* d_ws, size_t ws_size,
                              hipStream_t stream) {
    const float* x     = (const float*)d_in[0];
    const float* wm    = (const float*)d_in[1];
    // d_in[2] = bm: uniform pre-softmax shift -> no-op, skipped
    const float* w1    = (const float*)d_in[3];
    const float* b1    = (const float*)d_in[4];
    const float* ln_g  = (const float*)d_in[5];
    const float* ln_b  = (const float*)d_in[6];
    const float* w2    = (const float*)d_in[7];
    const float* b2    = (const float*)d_in[8];
    const float* gamma = (const float*)d_in[9];
    float* out = (float*)d_out;

    float* ws  = (float*)d_ws;
    float* pc  = ws;                               // kB*kNG*kC floats (6.4 MB)
    float* pmz = pc + (size_t)kB * kNG * kC;       // kB*kNG*2 floats
    float* add = pmz + (size_t)kB * kNG * 2;       // kB*kC floats

    k_pass_a<<<dim3(kNG, kB), 128, 0, stream>>>(x, wm, pc, pmz);
    k_combine_mlp<<<kB, 512, 0, stream>>>(pc, pmz, w1, b1, ln_g, ln_b,
                                          w2, b2, gamma, add);
    k_out<<<kOutBlocks, 256, 0, stream>>>(x, add, out);
}

// Round 6
// 396.541 us; speedup vs baseline: 1.4897x; 1.0437x over previous
//
#include <hip/hip_runtime.h>

constexpr int kB = 32;
constexpr int kC = 512;
constexpr int kS = 56 * 56;   // 3136
constexpr int kP = 64;
constexpr float kEps = 1e-3f;

constexpr int kSG = 32;          // spatial elems per block
constexpr int kNG = kS / kSG;    // 98 groups per batch
static_assert(kS % kSG == 0, "group must divide S");

typedef float f4v __attribute__((ext_vector_type(4)));

// ---------------------------------------------------------------------------
// Pass A v6: max-TLP register tile.
// Block = 512 thr (8 waves) owns 32 s x 512 c. Thread (c0 = t>>3 in 0..63,
// si = t&7): holds x[c = c0+64j][s0+si*4 ..+3], j = 0..7 -> 8 x f4 = 32 VGPR.
// 3136 blocks x 8 waves = 25088 waves, VGPR ~60 -> ~full occupancy (TLP is
// what ranked R1 > R5 > R4 across rounds 1-5; pass A is latency-bound).
// Per load instr: wave = 8 rows x 128B = 8 full lines, min request count.
//   phase 1: FMA vs swm; c-butterfly (shfl 8,16,32); LDS wave-exchange;
//            wave 0: combine 8 wave-partials + 32-wide softmax (lanes compute
//            redundantly per si-class; only l<8 / l==0 write).
//   phase 2: context from the SAME (pinned) registers; si-butterfly (1,2,4);
//            si==0 lanes store 8 consecutive floats per wave per j.
// ---------------------------------------------------------------------------
__global__ __launch_bounds__(512)
void k_pass_a(const float* __restrict__ x, const float* __restrict__ wm,
              float* __restrict__ pc, float* __restrict__ pmz) {
    __shared__ float swm[kC];
    __shared__ f4v   pmw[8][8];        // [wave][si] mask partials
    __shared__ f4v   es4[kSG / 4];     // exp(mask - M_loc)

    const int t  = threadIdx.x;
    const int w  = t >> 6;             // wave 0..7
    const int l  = t & 63;
    const int si = t & 7;              // f4 slot over the 32-s group
    const int c0 = t >> 3;             // 0..63
    const int b  = blockIdx.y;
    const int g  = blockIdx.x;
    const int s0 = g * kSG;

    swm[t] = wm[t];

    const float* xb = x + (size_t)b * kC * kS + (size_t)c0 * kS + s0 + si * 4;

    // ---- single global read: 8 independent loads in flight ----
    f4v xt[8];
#pragma unroll
    for (int j = 0; j < 8; ++j)
        xt[j] = *(const f4v*)(xb + (size_t)(64 * j) * kS);

    __syncthreads();                   // swm ready (loads drain under barrier)

    // ---- phase 1: mask partials over this thread's 8 c's ----
    float m0 = 0.f, m1 = 0.f, m2 = 0.f, m3 = 0.f;
#pragma unroll
    for (int j = 0; j < 8; ++j) {
        const float wv = swm[c0 + 64 * j];
        m0 += xt[j].x * wv; m1 += xt[j].y * wv;
        m2 += xt[j].z * wv; m3 += xt[j].w * wv;
    }

    // pin the tile: forbid rematerialization of the loads into phase 2
#pragma unroll
    for (int j = 0; j < 8; ++j) asm volatile("" : "+v"(xt[j]));

    // reduce over the wave's 8 c0 slots (lane bits 3..5)
#pragma unroll
    for (int off = 8; off <= 32; off <<= 1) {
        m0 += __shfl_xor(m0, off); m1 += __shfl_xor(m1, off);
        m2 += __shfl_xor(m2, off); m3 += __shfl_xor(m3, off);
    }
    if (l < 8) pmw[w][si] = (f4v){m0, m1, m2, m3};
    __syncthreads();

    // ---- wave 0: combine 8 wave-partials + local softmax over 32 s ----
    if (w == 0) {
        // every lane computes its si-class (lanes l and l+8k duplicate; the
        // off<=4 butterflies stay within each 8-lane group -> all valid)
        f4v mv = pmw[0][si];
#pragma unroll
        for (int ww = 1; ww < 8; ++ww) {
            const f4v o = pmw[ww][si];
            mv.x += o.x; mv.y += o.y; mv.z += o.z; mv.w += o.w;
        }
        float mm = fmaxf(fmaxf(mv.x, mv.y), fmaxf(mv.z, mv.w));
        mm = fmaxf(mm, __shfl_xor(mm, 1));
        mm = fmaxf(mm, __shfl_xor(mm, 2));
        mm = fmaxf(mm, __shfl_xor(mm, 4));
        const f4v e = {expf(mv.x - mm), expf(mv.y - mm),
                       expf(mv.z - mm), expf(mv.w - mm)};
        float z = e.x + e.y + e.z + e.w;
        z += __shfl_xor(z, 1); z += __shfl_xor(z, 2); z += __shfl_xor(z, 4);
        if (l < 8) es4[si] = e;
        if (l == 0) {
            pmz[(b * kNG + g) * 2 + 0] = mm;
            pmz[(b * kNG + g) * 2 + 1] = z;
        }
    }
    __syncthreads();

    // ---- phase 2: context from the SAME registers ----
    const f4v e4 = es4[si];
    float* pco = pc + ((size_t)b * kNG + g) * kC;
#pragma unroll
    for (int j = 0; j < 8; ++j) {
        float p = xt[j].x * e4.x + xt[j].y * e4.y + xt[j].z * e4.z + xt[j].w * e4.w;
        p += __shfl_xor(p, 1); p += __shfl_xor(p, 2); p += __shfl_xor(p, 4);
        if (si == 0) pco[c0 + 64 * j] = p;   // 8 lanes -> 8 consecutive floats
    }
}

// ---------------------------------------------------------------------------
// Pass B: per batch — combine 98 group-partials with global softmax rescale,
// then the tiny MLP (w1 -> LN -> ReLU -> w2), gamma folded into the output.
// ---------------------------------------------------------------------------
__global__ __launch_bounds__(512)
void k_combine_mlp(const float* __restrict__ pc, const float* __restrict__ pmz,
                   const float* __restrict__ w1, const float* __restrict__ b1,
                   const float* __restrict__ ln_g, const float* __restrict__ ln_b,
                   const float* __restrict__ w2, const float* __restrict__ b2,
                   const float* __restrict__ gamma, float* __restrict__ add) {
    const int b = blockIdx.x;
    const int t = threadIdx.x;
    __shared__ float scale[kNG];     // exp(M_i - M)/Z
    __shared__ float ctx[kC];
    __shared__ float hp[kP][9];      // hid partials (pad 9: bank-spread)
    __shared__ float hid[kP];

    // wave 0: global max + Z over 98 groups (two elems per lane)
    if (t < 64) {
        const float m1 = (t      < kNG) ? pmz[(b * kNG + t     ) * 2] : -INFINITY;
        const float m2 = (t + 64 < kNG) ? pmz[(b * kNG + t + 64) * 2] : -INFINITY;
        float m = fmaxf(m1, m2);
        for (int off = 32; off; off >>= 1) m = fmaxf(m, __shfl_xor(m, off));
        const float e1 = (t      < kNG) ? expf(m1 - m) : 0.f;
        const float e2 = (t + 64 < kNG) ? expf(m2 - m) : 0.f;
        float z = 0.f;
        if (t      < kNG) z += pmz[(b * kNG + t     ) * 2 + 1] * e1;
        if (t + 64 < kNG) z += pmz[(b * kNG + t + 64) * 2 + 1] * e2;
        for (int off = 32; off; off >>= 1) z += __shfl_xor(z, off);
        const float inv = 1.f / z;
        if (t      < kNG) scale[t]      = e1 * inv;
        if (t + 64 < kNG) scale[t + 64] = e2 * inv;
    }
    __syncthreads();

    // ctx[c] = sum_i pc[i][c] * scale[i]   (coalesced over c)
    {
        float acc = 0.f;
        for (int i = 0; i < kNG; ++i)
            acc += pc[((size_t)b * kNG + i) * kC + t] * scale[i];
        ctx[t] = acc;
    }
    __syncthreads();

    // hid partials: p = t&63, chunk k = t>>6 sums 64 c's (ctx read = broadcast)
    {
        const int p = t & 63, k = t >> 6;
        const float* w1p = w1 + p * kC + k * 64;
        const float* cxp = ctx + k * 64;
        float acc = 0.f;
#pragma unroll 8
        for (int i = 0; i < 64; ++i) acc += w1p[i] * cxp[i];
        hp[p][k] = acc;
    }
    __syncthreads();

    if (t < 64) {
        float h = b1[t];
#pragma unroll
        for (int k = 0; k < 8; ++k) h += hp[t][k];
        float mu = h;
        for (int off = 32; off; off >>= 1) mu += __shfl_xor(mu, off);
        mu *= (1.f / kP);
        const float d = h - mu;
        float var = d * d;
        for (int off = 32; off; off >>= 1) var += __shfl_xor(var, off);
        var *= (1.f / kP);
        const float hv = d * rsqrtf(var + kEps) * ln_g[t] + ln_b[t];
        hid[t] = fmaxf(hv, 0.f);
    }
    __syncthreads();

    // add[c] = gamma * (b2[c] + w2[c,:]·hid)   — gamma folded here
    {
        float a = b2[t];
        const float* w2c = w2 + t * kP;
#pragma unroll
        for (int p = 0; p < kP; ++p) a += w2c[p] * hid[p];
        add[b * kC + t] = gamma[0] * a;
    }
}

// ---------------------------------------------------------------------------
// Pass C: out = x + add[bc] (gamma pre-folded). Max-TLP form (measured best
// in R1): 50176 blocks x 256 thr, 1 f4 per thread. x read is L3-resident.
// ---------------------------------------------------------------------------
constexpr unsigned kN4 = (unsigned)((size_t)kB * kC * kS / 4);   // 12,845,056
static_assert((size_t)kN4 * 4 == (size_t)kB * kC * kS, "exact");
static_assert(kN4 % 256 == 0, "exact grid");

__global__ __launch_bounds__(256)
void k_out(const float* __restrict__ x, const float* __restrict__ addv,
           float* __restrict__ out) {
    const unsigned i4 = blockIdx.x * 256u + threadIdx.x;
    const float a = addv[i4 / (kS / 4)];           // /784 -> magic-mul
    const f4v xv = ((const f4v*)x)[i4];
    const f4v o = {xv.x + a, xv.y + a, xv.z + a, xv.w + a};
    __builtin_nontemporal_store(o, (f4v*)out + i4);
}

extern "C" void kernel_launch(void* const* d_in, const int* in_sizes, int n_in,
                              void* d_out, int out_size, void* d_ws, size_t ws_size,
                              hipStream_t stream) {
    const float* x     = (const float*)d_in[0];
    const float* wm    = (const float*)d_in[1];
    // d_in[2] = bm: uniform pre-softmax shift -> no-op, skipped
    const float* w1    = (const float*)d_in[3];
    const float* b1    = (const float*)d_in[4];
    const float* ln_g  = (const float*)d_in[5];
    const float* ln_b  = (const float*)d_in[6];
    const float* w2    = (const float*)d_in[7];
    const float* b2    = (const float*)d_in[8];
    const float* gamma = (const float*)d_in[9];
    float* out = (float*)d_out;

    float* ws  = (float*)d_ws;
    float* pc  = ws;                               // kB*kNG*kC floats (6.4 MB)
    float* pmz = pc + (size_t)kB * kNG * kC;       // kB*kNG*2 floats
    float* add = pmz + (size_t)kB * kNG * 2;       // kB*kC floats

    k_pass_a<<<dim3(kNG, kB), 512, 0, stream>>>(x, wm, pc, pmz);
    k_combine_mlp<<<kB, 512, 0, stream>>>(pc, pmz, w1, b1, ln_g, ln_b,
                                          w2, b2, gamma, add);
    k_out<<<kN4 / 256, 256, 0, stream>>>(x, add, out);
}